// Round 7
// baseline (339.989 us; speedup 1.0000x reference)
//
#include <hip/hip_runtime.h>

// Problem constants
#define NN 64
#define CC 64
#define TT 256
#define VV 25
#define RR 8
#define OO 64
#define PLANE 6400  // T*V per (n,c)
#define SX 101      // x3s row stride (floats). 64*101*4 = 25856B -> 6 blocks/CU.
#define MPS 832     // mp stride per (n,o): 26 rows x 32 (rows 0..24 = m[v][u],
                    // row 25 = b3[o]*sum_v m[u][v] for phase-2 acc init)

typedef _Float16 f16x8 __attribute__((ext_vector_type(8)));
typedef float f32x16 __attribute__((ext_vector_type(16)));

// ---------------------------------------------------------------------------
// Kernel A: xsum[n][c][v] = sum_t x[n][c][t][v]
// One block per (n,c). float4-stage the plane into LDS, tree reduction.
// Blocks 0..15 also convert w3 -> fp16 (natural [o][c] layout, used as the
// MFMA A-operand in k_fused).
// ---------------------------------------------------------------------------
__global__ __launch_bounds__(256) void k_xsum(const float* __restrict__ x,
                                              float* __restrict__ xsum,
                                              const float* __restrict__ w3,
                                              _Float16* __restrict__ w3h) {
  int nc = blockIdx.x;  // n*64 + c
  int tid = threadIdx.x;
  if (blockIdx.x < 16) {
    int k = blockIdx.x * 256 + tid;  // < 4096, w3 is [o][c] row-major
    w3h[k] = (_Float16)w3[k];
  }
  const float4* src4 = (const float4*)(x + (size_t)nc * PLANE);
  __shared__ __align__(16) float s[PLANE + 256];
  float4* s4 = (float4*)s;
  for (int k = tid; k < PLANE / 4; k += 256) s4[k] = src4[k];
  __syncthreads();
  if (tid < 200) {
    int tg = tid / 25, v = tid - tg * 25;
    float a0 = 0.f, a1 = 0.f, a2 = 0.f, a3 = 0.f;
    for (int k = 0; k < 32; k += 4) {
      a0 += s[(tg + 8 * (k + 0)) * VV + v];
      a1 += s[(tg + 8 * (k + 1)) * VV + v];
      a2 += s[(tg + 8 * (k + 2)) * VV + v];
      a3 += s[(tg + 8 * (k + 3)) * VV + v];
    }
    s[PLANE + tid] = (a0 + a1) + (a2 + a3);
  }
  __syncthreads();
  if (tid < VV) {
    float a = 0.f;
#pragma unroll
    for (int g = 0; g < 8; ++g) a += s[PLANE + g * VV + tid];
    xsum[nc * VV + tid] = a;
  }
}

// ---------------------------------------------------------------------------
// Kernel B: build m, layout mp[n][o][v][32] (word u = m[n,o,u,v]); extra row
// v=25 holds b3[o]*sum_v m[u][v] (phase-2 accumulator init -- this is how b3
// of conv3 enters the output: out = sum_v m*x3' + b3*sum_v m).
// Grid (n, og): each block computes 8 o's.
// ---------------------------------------------------------------------------
__global__ __launch_bounds__(256) void k_build_m(
    const float* __restrict__ xsum, const float* __restrict__ A,
    const float* __restrict__ w1, const float* __restrict__ b1,
    const float* __restrict__ w2, const float* __restrict__ b2,
    const float* __restrict__ b3, const float* __restrict__ w4,
    const float* __restrict__ b4, float* __restrict__ mp) {
  int n = blockIdx.x;
  int og = blockIdx.y;             // o-group: o in [og*8, og*8+8)
  __shared__ float xs[CC * VV];    // 1600
  __shared__ float sx1[RR * VV];   // 200
  __shared__ float sx2[RR * VV];   // 200
  __shared__ float att[RR * 625];  // 5000
  int tid = threadIdx.x;
  const float* xsn = xsum + n * (CC * VV);
  for (int k = tid; k < CC * VV; k += 256) xs[k] = xsn[k];
  __syncthreads();
  if (tid < RR * VV) {
    int r = tid / VV, v = tid % VV;
    float a1 = 0.f, a2 = 0.f;
#pragma unroll
    for (int c = 0; c < CC; ++c) {
      float xv = xs[c * VV + v];
      a1 = fmaf(w1[r * CC + c], xv, a1);
      a2 = fmaf(w2[r * CC + c], xv, a2);
    }
    sx1[tid] = a1 * (1.f / 256.f) + b1[r];
    sx2[tid] = a2 * (1.f / 256.f) + b2[r];
  }
  __syncthreads();
  for (int k = tid; k < RR * 625; k += 256) {
    int r = k / 625, uv = k % 625;
    int u = uv / VV, v = uv % VV;
    att[k] = tanhf(sx1[r * VV + u] - sx2[r * VV + v]);
  }
  __syncthreads();
  for (int k = tid; k < 8 * 625; k += 256) {
    int o = og * 8 + k / 625, vu = k % 625;
    int v = vu / VV, u = vu % VV;
    float a = b4[o] + A[u * VV + v];
#pragma unroll
    for (int r = 0; r < RR; ++r)
      a = fmaf(w4[o * RR + r], att[r * 625 + u * VV + v], a);
    mp[(size_t)(n * OO + o) * MPS + v * 32 + u] = a;
  }
  // b3-fold row: mb3[u] = b3[o] * sum_v m[u][v]. __syncthreads drains vmcnt
  // so this block's mp writes above are visible (same-block readback).
  __syncthreads();
  if (tid < 200) {
    int ol = tid / 25, u = tid % 25;
    int o = og * 8 + ol;
    const float* row = mp + (size_t)(n * OO + o) * MPS;
    float sum = 0.f;
#pragma unroll
    for (int v = 0; v < VV; ++v) sum += row[v * 32 + u];
    mp[(size_t)(n * OO + o) * MPS + 800 + u] = b3[o] * sum;
  }
}

// ---------------------------------------------------------------------------
// Kernel F (fused conv3 + aggregation): block = (t-tile of 4 rows, n).
// Round-6 post-mortem: all pipes <35% -> latency-bound on 3 barrier drains
// per block. This version has ONE barrier per block:
// Phase 1: conv3 via MFMA (FULL ks unroll: all 32 x-loads issue before the
//   first MFMA -> single HBM latency hump). x3 -> LDS s[o][p].
// Phase 2: lane (o=tid>>2, uq=tid&3); m rows as float4 (#pragma unroll 5 ->
//   ~10 loads in flight covers L2 latency); acc inits from the b3-fold row;
//   DIRECT scalar stores to out (no LDS round trip, no store barrier --
//   float4 stores are not 16B-aligned here anyway; L2 write-combines the
//   (o,t)-row scalars). Removes 2 of 3 barriers + ~100 LDS ops/thread.
// ---------------------------------------------------------------------------
__global__ __launch_bounds__(256, 6) void k_fused(
    const float* __restrict__ x, const _Float16* __restrict__ w3h,
    const float* __restrict__ mp, float* __restrict__ out) {
  int n = blockIdx.y;
  int t0 = blockIdx.x * 4;      // 64 tiles of 4 t-rows
  __shared__ float s[OO * SX];  // 25856 B -> 6 blocks/CU
  int tid = threadIdx.x;

  // ---- phase 1: conv3 via MFMA
  {
    int lane = tid & 63;
    int pt = tid >> 6;                  // wave id = p-tile
    int p = pt * 32 + (lane & 31);      // this lane's output column
    int pc = p < 100 ? p : 99;          // clamp pad lanes in-bounds
    int chalf = (lane >> 5) * 8;        // k-row group within a k-step
    const float* xb = x + (size_t)n * CC * PLANE + t0 * VV + pc;
    const _Float16* wa0 = w3h + (lane & 31) * 64 + chalf;        // o-tile 0
    const _Float16* wa1 = w3h + ((lane & 31) + 32) * 64 + chalf; // o-tile 1
    f32x16 acc0 = {0, 0, 0, 0, 0, 0, 0, 0, 0, 0, 0, 0, 0, 0, 0, 0};
    f32x16 acc1 = {0, 0, 0, 0, 0, 0, 0, 0, 0, 0, 0, 0, 0, 0, 0, 0};
#pragma unroll
    for (int ks = 0; ks < 4; ++ks) {
      float xv[8];
#pragma unroll
      for (int e = 0; e < 8; ++e)
        xv[e] = xb[(size_t)(ks * 16 + chalf + e) * PLANE];
      f16x8 bf;
#pragma unroll
      for (int e = 0; e < 8; ++e) bf[e] = (_Float16)xv[e];
      f16x8 a0 = *(const f16x8*)(wa0 + ks * 16);
      f16x8 a1 = *(const f16x8*)(wa1 + ks * 16);
      acc0 = __builtin_amdgcn_mfma_f32_32x32x16_f16(a0, bf, acc0, 0, 0, 0);
      acc1 = __builtin_amdgcn_mfma_f32_32x32x16_f16(a1, bf, acc1, 0, 0, 0);
    }
    if (p < 100) {
#pragma unroll
      for (int r = 0; r < 16; ++r) {
        int row = (r & 3) + 8 * (r >> 2) + 4 * (lane >> 5);
        s[row * SX + p] = acc0[r];
        s[(row + 32) * SX + p] = acc1[r];
      }
    }
  }
  __syncthreads();  // the ONLY barrier: x3 tile complete

  // ---- phase 2: out[t][u] = sum_v m[o][u][v] * x3[o][t][v]  (+ b3-fold),
  //      direct stores
  {
    int o = tid >> 2, uq = tid & 3;
    const float* mb = mp + (size_t)(n * OO + o) * MPS + uq * 8;
    const float* xr = s + o * SX;
    float4 i0 = *(const float4*)(mb + 800);
    float4 i1 = *(const float4*)(mb + 804);
    float acc[4][8];
#pragma unroll
    for (int t = 0; t < 4; ++t) {
      acc[t][0] = i0.x; acc[t][1] = i0.y; acc[t][2] = i0.z; acc[t][3] = i0.w;
      acc[t][4] = i1.x; acc[t][5] = i1.y; acc[t][6] = i1.z; acc[t][7] = i1.w;
    }
#pragma unroll 5
    for (int v = 0; v < VV; ++v) {
      float4 m0 = *(const float4*)(mb + v * 32);
      float4 m1 = *(const float4*)(mb + v * 32 + 4);
      float xt[4];
#pragma unroll
      for (int t = 0; t < 4; ++t) xt[t] = xr[t * VV + v];
#pragma unroll
      for (int t = 0; t < 4; ++t) {
        acc[t][0] = fmaf(m0.x, xt[t], acc[t][0]);
        acc[t][1] = fmaf(m0.y, xt[t], acc[t][1]);
        acc[t][2] = fmaf(m0.z, xt[t], acc[t][2]);
        acc[t][3] = fmaf(m0.w, xt[t], acc[t][3]);
        acc[t][4] = fmaf(m1.x, xt[t], acc[t][4]);
        acc[t][5] = fmaf(m1.y, xt[t], acc[t][5]);
        acc[t][6] = fmaf(m1.z, xt[t], acc[t][6]);
        acc[t][7] = fmaf(m1.w, xt[t], acc[t][7]);
      }
    }
    // Direct scalar stores: (o,t) row floats u = uq*8 .. uq*8+7 (u<25).
    // uq==3 contributes only u=24. L2 merges the row's scalars into full
    // lines (4 consecutive t-rows per o-plane are written by this block).
    float* ob = out + (size_t)(n * OO + o) * PLANE + t0 * VV + uq * 8;
    if (uq < 3) {
#pragma unroll
      for (int t = 0; t < 4; ++t)
#pragma unroll
        for (int j = 0; j < 8; ++j) ob[t * VV + j] = acc[t][j];
    } else {
#pragma unroll
      for (int t = 0; t < 4; ++t) ob[t * VV] = acc[t][0];
    }
  }
}

extern "C" void kernel_launch(void* const* d_in, const int* in_sizes, int n_in,
                              void* d_out, int out_size, void* d_ws,
                              size_t ws_size, hipStream_t stream) {
  const float* x = (const float*)d_in[0];
  const float* A = (const float*)d_in[1];
  const float* w1 = (const float*)d_in[2];
  const float* b1 = (const float*)d_in[3];
  const float* w2 = (const float*)d_in[4];
  const float* b2 = (const float*)d_in[5];
  const float* w3 = (const float*)d_in[6];
  const float* b3 = (const float*)d_in[7];
  const float* w4 = (const float*)d_in[8];
  const float* b4 = (const float*)d_in[9];
  float* out = (float*)d_out;
  float* ws = (float*)d_ws;

  float* xsum = ws;                       // 64*64*25 = 102400 floats
  _Float16* w3h = (_Float16*)(ws + 102400);  // 4096 halfs = 2048 float slots
  float* mp = ws + 102400 + 2048;         // 64*64*832 floats (13.6 MB)

  k_xsum<<<NN * CC, 256, 0, stream>>>(x, xsum, w3, w3h);
  k_build_m<<<dim3(NN, 8), 256, 0, stream>>>(xsum, A, w1, b1, w2, b2, b3, w4,
                                             b4, mp);
  k_fused<<<dim3(TT / 4, NN), 256, 0, stream>>>(x, w3h, mp, out);
}